// Round 13
// baseline (180.615 us; speedup 1.0000x reference)
//
#include <hip/hip_runtime.h>
#include <math.h>

// DigitCaps dynamic routing, MI355X. Round 12: multi-pass blocks — stage
// W'[j] ONCE per block (64 KB LDS), then ~5 barrier-free passes over b.
// u[B=128, R=864, I=4] f32, W[1, J=166, R=864, O=8, I=4] f32 -> v[128,166,8] f32.
//
// Round-11 post-mortem: the 4-waves/4-barriers-per-(j,4b) structure plateaus
// at ~89 us (55% VALU busy, ~40 us unremovable barrier/latency stall; W[j]
// re-staged 32x per j). Round 12: 512 blocks x 512 threads (exactly 2
// blocks/CU by LDS and launch_bounds), block handles a contiguous range of
// ~5 passes (pass = one j, 8 b, one b per wave). W'[j] staged once per j
// change (~2 stagings/block, ~2-3 barriers/block TOTAL); passes run with no
// synchronization at all.
// LDS: full W'[j] as [o][r] rows padded to 1024 uint2 (64 KB; DMA'd with
// 16 B global_load_lds, lane-order contiguous, conflict-free b64 reads).
// Kept from prior rounds: W-only pre-pack kernel (W'[j][o][r] fp16-pair
// uint2, 9.2 MB ws), u_hat packed fp16 in uint32 regs with compile-time
// indices only (round-4 spill lesson; WRITE_SIZE = spill tripwire),
// b_r = <u_hat, V> dot2 routing with running V, no softmax max-pass
// (shift-invariant, |b_r| small, fp32 exp).

#define BB 128
#define JJ 166
#define RR 864
#define OO 8
#define KMAX 14            // ceil(864/64); k=13 has only lanes 0..31 valid
#define ROWU2 1024         // LDS row stride in uint2 (864 used, padded)
#define NPASS (JJ * 16)    // 2656; pass = (j, 8 consecutive b)
#define GRID 512

typedef __fp16 h2v __attribute__((ext_vector_type(2)));

__device__ __forceinline__ uint32_t pack2(float a, float b) {
    return __builtin_bit_cast(uint32_t, __builtin_amdgcn_cvt_pkrtz(a, b));
}
__device__ __forceinline__ h2v bc_h2(uint32_t u) {
    return __builtin_bit_cast(h2v, u);
}
__device__ __forceinline__ float lo_f(uint32_t u) {
    return (float)__builtin_bit_cast(h2v, u).x;
}
__device__ __forceinline__ float hi_f(uint32_t u) {
    return (float)__builtin_bit_cast(h2v, u).y;
}

__device__ __forceinline__ float wave_sum(float v) {
#pragma unroll
    for (int m = 32; m >= 1; m >>= 1) v += __shfl_xor(v, m, 64);
    return v;
}

// ---- pre-kernel: W [J][R][O][I] f32 -> W'[j][o][r] fp16-pair uint2 ----
#define WBLOCKS 4482   // J*R*O/256
__global__ __launch_bounds__(256) void pack_kernel(
    const float4* __restrict__ W4, uint2* __restrict__ Wp) {
    const int t = blockIdx.x * 256 + threadIdx.x;  // < J*R*O
    const float4 w = W4[t];
    const int o = t & 7;
    const int jr = t >> 3;
    const int r = jr % RR;
    const int j = jr / RR;
    Wp[(j * OO + o) * RR + r] = make_uint2(pack2(w.x, w.y), pack2(w.z, w.w));
}

__global__ __launch_bounds__(512, 4) void digitcaps_kernel(
    const uint2* __restrict__ Wp, const float* __restrict__ u,
    float* __restrict__ out) {
    const int tid = threadIdx.x;
    const int lane = tid & 63;
    const int wave = tid >> 6;

    const float4* __restrict__ u4 = (const float4*)u;  // [B][R]

    // full W'[j]: [o][rl], rows padded to 1024 uint2 -> 64 KB, 2 blocks/CU
    __shared__ uint2 wlds[OO * ROWU2];

    // contiguous pass range for this block (5 or 6 passes, mostly same j)
    const int p0 = (int)(((long)blockIdx.x * NPASS) >> 9);
    const int p1 = (int)(((long)(blockIdx.x + 1) * NPASS) >> 9);

    int jcur = -1;
    for (int p = p0; p < p1; ++p) {
        const int j = p >> 4;                   // 16 passes per j
        const int b = ((p & 15) << 3) + wave;   // 8 b per pass

        if (j != jcur) {
            if (jcur >= 0) __syncthreads();  // all waves done reading old W
            // stage full W'[j]: per o-row, threads 0..431 issue one 16 B DMA
            // (432*2 = 864 uint2). LDS dest wave-uniform base + lane*16 B.
            if (tid < 432) {
#pragma unroll
                for (int o = 0; o < OO; ++o) {
                    const uint2* gsrc = Wp + (j * OO + o) * RR + (tid << 1);
                    uint2* ldst = &wlds[(o << 10) + (wave << 7)];
                    __builtin_amdgcn_global_load_lds(
                        (const __attribute__((address_space(1))) uint32_t*)gsrc,
                        (__attribute__((address_space(3))) uint32_t*)ldst,
                        16, 0, 0);
                }
            }
            __syncthreads();  // drains DMA (vmcnt(0) before s_barrier)
            jcur = j;
        }

        // ---- u_hat for this (b,j): pure LDS + register work ----
        uint32_t uh[KMAX][4];  // packed fp16 pairs; constant indices only
        float acc[OO];         // iteration-0 per-lane route sums (f32)
#pragma unroll
        for (int o = 0; o < OO; ++o) acc[o] = 0.0f;

#pragma unroll
        for (int kl = 0; kl < KMAX; ++kl) {
            const int rl = (kl << 6) + lane;
            const bool valid = (kl < KMAX - 1) || (lane < 32);
            const float4 uu4 = u4[b * RR + (valid ? rl : 0)];
            const uint32_t up0 = pack2(uu4.x, uu4.y);
            const uint32_t up1 = pack2(uu4.z, uu4.w);
            float d[OO];
#pragma unroll
            for (int o = 0; o < OO; ++o) {
                const uint2 ww = wlds[(o << 10) + rl];
                float t0 = __builtin_amdgcn_fdot2(bc_h2(ww.x), bc_h2(up0),
                                                  0.0f, false);
                d[o] = __builtin_amdgcn_fdot2(bc_h2(ww.y), bc_h2(up1), t0,
                                              false);
            }
            if (valid) {
#pragma unroll
                for (int o = 0; o < OO; ++o) acc[o] += d[o];
#pragma unroll
                for (int o2 = 0; o2 < 4; ++o2)
                    uh[kl][o2] = pack2(d[2 * o2], d[2 * o2 + 1]);
            } else {
#pragma unroll
                for (int o2 = 0; o2 < 4; ++o2) uh[kl][o2] = 0u;
            }
        }

        float V[OO];  // running sum of past v's (b_r = <uhat_r, V>)
        float v[OO];

        // ---- iteration 0: b=0 -> c uniform = 1/R ----
        {
            float s[OO];
#pragma unroll
            for (int o = 0; o < OO; ++o)
                s[o] = wave_sum(acc[o]) * (1.0f / (float)RR);

            float n2 = 0.0f;
#pragma unroll
            for (int o = 0; o < OO; ++o) n2 += s[o] * s[o];
            const float scale = sqrtf(n2) / (1.0f + n2);
#pragma unroll
            for (int o = 0; o < OO; ++o) { v[o] = s[o] * scale; V[o] = v[o]; }
        }

        // ---- iterations 1 and 2 ----
#pragma unroll
        for (int it = 1; it < 3; ++it) {
            uint32_t Vp[4];
#pragma unroll
            for (int o2 = 0; o2 < 4; ++o2)
                Vp[o2] = pack2(V[2 * o2], V[2 * o2 + 1]);

            float zp = 0.0f;
            float sp[OO];
#pragma unroll
            for (int o = 0; o < OO; ++o) sp[o] = 0.0f;

#pragma unroll
            for (int k = 0; k < KMAX; ++k) {
                float br = 0.0f;
#pragma unroll
                for (int o2 = 0; o2 < 4; ++o2)
                    br = __builtin_amdgcn_fdot2(bc_h2(uh[k][o2]),
                                                bc_h2(Vp[o2]), br, false);
                // mask invalid routes (k==13, lane>=32): exp(0)=1 pollutes Z
                const float e = (k < KMAX - 1 || lane < 32) ? __expf(br) : 0.0f;
                zp += e;
#pragma unroll
                for (int o2 = 0; o2 < 4; ++o2) {
                    sp[2 * o2]     = fmaf(e, lo_f(uh[k][o2]), sp[2 * o2]);
                    sp[2 * o2 + 1] = fmaf(e, hi_f(uh[k][o2]), sp[2 * o2 + 1]);
                }
            }
            const float invZ = 1.0f / wave_sum(zp);

            float s[OO];
#pragma unroll
            for (int o = 0; o < OO; ++o) s[o] = wave_sum(sp[o]) * invZ;

            float n2 = 0.0f;
#pragma unroll
            for (int o = 0; o < OO; ++o) n2 += s[o] * s[o];
            const float scale = sqrtf(n2) / (1.0f + n2);
#pragma unroll
            for (int o = 0; o < OO; ++o) v[o] = s[o] * scale;

            if (it < 2) {
#pragma unroll
                for (int o = 0; o < OO; ++o) V[o] += v[o];
            }
        }

        // ---- write out[b][j][o] ----
        float outv = 0.0f;
#pragma unroll
        for (int o = 0; o < OO; ++o)
            if (lane == o) outv = v[o];
        if (lane < OO) out[(b * JJ + j) * OO + lane] = outv;
    }
}

extern "C" void kernel_launch(void* const* d_in, const int* in_sizes, int n_in,
                              void* d_out, int out_size, void* d_ws, size_t ws_size,
                              hipStream_t stream) {
    const float* u = (const float*)d_in[0];  // [128, 864, 4]
    const float* W = (const float*)d_in[1];  // [1, 166, 864, 8, 4]
    float* out = (float*)d_out;              // [128, 166, 8]

    uint2* Wp = (uint2*)d_ws;                // 9,179,136 B workspace

    pack_kernel<<<WBLOCKS, 256, 0, stream>>>((const float4*)W, Wp);

    digitcaps_kernel<<<GRID, 512, 0, stream>>>(Wp, u, out);
}